// Round 1
// baseline (346.839 us; speedup 1.0000x reference)
//
#include <hip/hip_runtime.h>
#include <hip/hip_bf16.h>
#include <stdint.h>

#define BB 4
#define SS 4096
#define EE 1024
#define DD 64
#define QBLK 32
#define KVT 64

typedef __attribute__((ext_vector_type(8))) short short8;
typedef __attribute__((ext_vector_type(4))) float f32x4;

__device__ inline ushort f2bf(float f) {
    union { float f; uint32_t u; } v; v.f = f;
    uint32_t r = (v.u + 0x7FFFu + ((v.u >> 16) & 1u)) >> 16;
    return (ushort)r;
}

// ---------------- Projection: q,k = x@W^T (bf16 [B,S,D]); v stored transposed [B,D,S] ----------------
__global__ __launch_bounds__(256) void proj_kernel(
    const float* __restrict__ x, const float* __restrict__ Wk,
    const float* __restrict__ Wq, const float* __restrict__ Wv,
    ushort* __restrict__ q_ws, ushort* __restrict__ k_ws, ushort* __restrict__ vT_ws)
{
    __shared__ __align__(16) ushort x_lds[64][72];
    __shared__ __align__(16) ushort w_lds[192][72];
    const int t = threadIdx.x;
    const int wid = t >> 6;
    const int lane = t & 63;
    const int g = lane >> 4;
    const int lr = lane & 15;
    const int m0 = blockIdx.x * 64;

    f32x4 acc[12];
#pragma unroll
    for (int i = 0; i < 12; ++i) acc[i] = (f32x4)(0.0f);

    for (int e0 = 0; e0 < EE; e0 += 64) {
        // stage x tile 64x64 f32 -> bf16 LDS
#pragma unroll
        for (int i = 0; i < 4; ++i) {
            int idx = i * 256 + t;          // 0..1023 (float4 units)
            int row = idx >> 4;             // 16 float4 per 64-elem row
            int c4 = idx & 15;
            float4 v = *reinterpret_cast<const float4*>(&x[(size_t)(m0 + row) * EE + e0 + c4 * 4]);
            ushort* dst = &x_lds[row][c4 * 4];
            dst[0] = f2bf(v.x); dst[1] = f2bf(v.y); dst[2] = f2bf(v.z); dst[3] = f2bf(v.w);
        }
        // stage W tile 192x64 (rows 0-63: Wq, 64-127: Wk, 128-191: Wv)
#pragma unroll
        for (int i = 0; i < 12; ++i) {
            int idx = i * 256 + t;          // 0..3071
            int row = idx >> 4;             // 0..191
            int c4 = idx & 15;
            const float* wp = (row < 64) ? Wq : ((row < 128) ? Wk : Wv);
            int wr = row & 63;
            float4 v = *reinterpret_cast<const float4*>(&wp[(size_t)wr * EE + e0 + c4 * 4]);
            ushort* dst = &w_lds[row][c4 * 4];
            dst[0] = f2bf(v.x); dst[1] = f2bf(v.y); dst[2] = f2bf(v.z); dst[3] = f2bf(v.w);
        }
        __syncthreads();

        short8 a0 = *reinterpret_cast<const short8*>(&x_lds[wid * 16 + lr][g * 8]);
        short8 a1 = *reinterpret_cast<const short8*>(&x_lds[wid * 16 + lr][32 + g * 8]);
#pragma unroll
        for (int nf = 0; nf < 12; ++nf) {
            short8 b0 = *reinterpret_cast<const short8*>(&w_lds[nf * 16 + lr][g * 8]);
            short8 b1 = *reinterpret_cast<const short8*>(&w_lds[nf * 16 + lr][32 + g * 8]);
            acc[nf] = __builtin_amdgcn_mfma_f32_16x16x32_bf16(a0, b0, acc[nf], 0, 0, 0);
            acc[nf] = __builtin_amdgcn_mfma_f32_16x16x32_bf16(a1, b1, acc[nf], 0, 0, 0);
        }
        __syncthreads();
    }

    // epilogue: C/D layout col=lr, row=4*g+jr
#pragma unroll
    for (int nf = 0; nf < 12; ++nf) {
        int d = (nf & 3) * 16 + lr;
        int sel = nf >> 2;                  // 0=q, 1=k, 2=v
#pragma unroll
        for (int jr = 0; jr < 4; ++jr) {
            int m = m0 + wid * 16 + g * 4 + jr;
            int b = m >> 12;
            int s = m & (SS - 1);
            ushort val = f2bf(acc[nf][jr]);
            if (sel == 0)      q_ws[(size_t)(b * SS + s) * DD + d] = val;
            else if (sel == 1) k_ws[(size_t)(b * SS + s) * DD + d] = val;
            else               vT_ws[((size_t)b * DD + d) * SS + s] = val;
        }
    }
}

// ---------------- Flash attention, causal ----------------
__global__ __launch_bounds__(128) void attn_kernel(
    const ushort* __restrict__ q_ws, const ushort* __restrict__ k_ws,
    const ushort* __restrict__ vT_ws, float* __restrict__ out)
{
    __shared__ __align__(16) ushort K_lds[64][72];
    __shared__ __align__(16) ushort V_lds[64][72];   // holds V^T tile: [d][kv]
    __shared__ __align__(16) ushort P_lds[2][16][72];
    const int t = threadIdx.x;
    const int wid = t >> 6;
    const int lane = t & 63;
    const int g = lane >> 4, lr = lane & 15;
    const int bid = blockIdx.x;
    const int b = bid & (BB - 1);
    const int qt = (SS / QBLK - 1) - (bid >> 2);   // heavy tiles first
    const int qb = qt * QBLK;
    const int qrow0 = qb + wid * 16;

    // Q fragments (rows lr, k = 8g+j within 32-chunks)
    const ushort* qp = q_ws + (size_t)(b * SS + qrow0 + lr) * DD;
    short8 qf0 = *reinterpret_cast<const short8*>(qp + g * 8);
    short8 qf1 = *reinterpret_cast<const short8*>(qp + 32 + g * 8);

    float m_r[4], l_r[4];
    f32x4 acc[4];
#pragma unroll
    for (int i = 0; i < 4; ++i) { m_r[i] = -1e30f; l_r[i] = 0.0f; acc[i] = (f32x4)(0.0f); }

    const float sc = 0.125f * 1.44269504f;  // D^-0.5 * log2(e)

    const int nt = (qb + QBLK + KVT - 1) / KVT;
    for (int kt = 0; kt < nt; ++kt) {
        const int kv0 = kt * KVT;
        // stage K tile (contiguous 8KB) into padded LDS
        {
            const ushort* kp = k_ws + (size_t)(b * SS + kv0) * DD;
#pragma unroll
            for (int i = 0; i < 4; ++i) {
                int idx = i * 128 + t;            // 8-elem chunks
                int row = idx >> 3, c8 = idx & 7;
                *reinterpret_cast<uint4*>(&K_lds[row][c8 * 8]) =
                    *reinterpret_cast<const uint4*>(kp + idx * 8);
            }
            // stage V^T tile: rows d, cols kv
#pragma unroll
            for (int i = 0; i < 4; ++i) {
                int idx = i * 128 + t;
                int row = idx >> 3, c8 = idx & 7;
                *reinterpret_cast<uint4*>(&V_lds[row][c8 * 8]) =
                    *reinterpret_cast<const uint4*>(&vT_ws[((size_t)b * DD + row) * SS + kv0 + c8 * 8]);
            }
        }
        __syncthreads();

        // S = Q K^T  (B-frag rows of K_lds)
        f32x4 sfr[4];
#pragma unroll
        for (int nf = 0; nf < 4; ++nf) {
            short8 b0 = *reinterpret_cast<const short8*>(&K_lds[nf * 16 + lr][g * 8]);
            short8 b1 = *reinterpret_cast<const short8*>(&K_lds[nf * 16 + lr][32 + g * 8]);
            f32x4 s = (f32x4)(0.0f);
            s = __builtin_amdgcn_mfma_f32_16x16x32_bf16(qf0, b0, s, 0, 0, 0);
            s = __builtin_amdgcn_mfma_f32_16x16x32_bf16(qf1, b1, s, 0, 0, 0);
            sfr[nf] = s;
        }
        // scale (log2 domain) + causal mask
#pragma unroll
        for (int nf = 0; nf < 4; ++nf) {
            int kvg = kv0 + nf * 16 + lr;
#pragma unroll
            for (int jr = 0; jr < 4; ++jr) {
                int qg = qrow0 + g * 4 + jr;
                float v = sfr[nf][jr] * sc;
                if (kvg > qg) v = -1e30f;
                sfr[nf][jr] = v;
            }
        }
        // online softmax (per row jr, reduce across 16-lane group)
        float p[4][4];
#pragma unroll
        for (int jr = 0; jr < 4; ++jr) {
            float mt = fmaxf(fmaxf(sfr[0][jr], sfr[1][jr]), fmaxf(sfr[2][jr], sfr[3][jr]));
            mt = fmaxf(mt, __shfl_xor(mt, 1));
            mt = fmaxf(mt, __shfl_xor(mt, 2));
            mt = fmaxf(mt, __shfl_xor(mt, 4));
            mt = fmaxf(mt, __shfl_xor(mt, 8));
            float mn = fmaxf(m_r[jr], mt);
            float sf = exp2f(m_r[jr] - mn);
            float ps = 0.0f;
#pragma unroll
            for (int nf = 0; nf < 4; ++nf) {
                float e = exp2f(sfr[nf][jr] - mn);
                p[nf][jr] = e;
                ps += e;
            }
            ps += __shfl_xor(ps, 1); ps += __shfl_xor(ps, 2);
            ps += __shfl_xor(ps, 4); ps += __shfl_xor(ps, 8);
            l_r[jr] = l_r[jr] * sf + ps;
            m_r[jr] = mn;
#pragma unroll
            for (int df = 0; df < 4; ++df) acc[df][jr] *= sf;
        }
        // P -> per-wave LDS (row = 4g+jr, col = nf*16+lr)
#pragma unroll
        for (int nf = 0; nf < 4; ++nf)
#pragma unroll
            for (int jr = 0; jr < 4; ++jr)
                P_lds[wid][g * 4 + jr][nf * 16 + lr] = f2bf(p[nf][jr]);
        asm volatile("s_waitcnt lgkmcnt(0)" ::: "memory");

        // O += P V   (A from P_lds rows lr; B from V^T rows d)
#pragma unroll
        for (int c = 0; c < 2; ++c) {
            short8 pa = *reinterpret_cast<const short8*>(&P_lds[wid][lr][c * 32 + g * 8]);
#pragma unroll
            for (int df = 0; df < 4; ++df) {
                short8 vb = *reinterpret_cast<const short8*>(&V_lds[df * 16 + lr][c * 32 + g * 8]);
                acc[df] = __builtin_amdgcn_mfma_f32_16x16x32_bf16(pa, vb, acc[df], 0, 0, 0);
            }
        }
        __syncthreads();
    }

    // epilogue
#pragma unroll
    for (int jr = 0; jr < 4; ++jr) {
        float inv = 1.0f / l_r[jr];
        int qg = qrow0 + g * 4 + jr;
        float* op = out + (size_t)(b * SS + qg) * DD;
#pragma unroll
        for (int df = 0; df < 4; ++df)
            op[df * 16 + lr] = acc[df][jr] * inv;
    }
}

extern "C" void kernel_launch(void* const* d_in, const int* in_sizes, int n_in,
                              void* d_out, int out_size, void* d_ws, size_t ws_size,
                              hipStream_t stream) {
    const float* x  = (const float*)d_in[0];
    const float* Wk = (const float*)d_in[1];
    const float* Wq = (const float*)d_in[2];
    const float* Wv = (const float*)d_in[3];
    ushort* q_ws  = (ushort*)d_ws;
    ushort* k_ws  = q_ws + (size_t)BB * SS * DD;
    ushort* vT_ws = k_ws + (size_t)BB * SS * DD;
    float* out = (float*)d_out;

    hipLaunchKernelGGL(proj_kernel, dim3(BB * SS / 64), dim3(256), 0, stream,
                       x, Wk, Wq, Wv, q_ws, k_ws, vT_ws);
    hipLaunchKernelGGL(attn_kernel, dim3(BB * SS / QBLK), dim3(128), 0, stream,
                       q_ws, k_ws, vT_ws, out);
}

// Round 2
// 115.496 us; speedup vs baseline: 3.0030x; 3.0030x over previous
//
#include <hip/hip_runtime.h>
#include <hip/hip_bf16.h>
#include <stdint.h>

#define BB 4
#define SS 4096
#define EE 1024
#define DD 64

typedef __attribute__((ext_vector_type(8))) short short8;
typedef __attribute__((ext_vector_type(4))) float f32x4;

__device__ inline uint32_t cvtpk(float lo, float hi) {
    uint32_t r;
    asm("v_cvt_pk_bf16_f32 %0, %1, %2" : "=v"(r) : "v"(lo), "v"(hi));
    return r;
}

#define SWZ16(r, bc) ((bc) ^ (((r) & 7) << 4))

// ---------- W f32 -> bf16 concat [192][1024]: rows 0-63 Wq, 64-127 Wk, 128-191 Wv ----------
__global__ __launch_bounds__(256) void wconv_kernel(
    const float* __restrict__ Wq, const float* __restrict__ Wk,
    const float* __restrict__ Wv, ushort* __restrict__ Wb)
{
    int tid = blockIdx.x * 256 + threadIdx.x;      // 24576 threads x 8 elems
    int sel = tid >> 13;
    int off = (tid & 8191) * 8;
    const float* src = (sel == 0) ? Wq : ((sel == 1) ? Wk : Wv);
    float4 a = *reinterpret_cast<const float4*>(src + off);
    float4 b = *reinterpret_cast<const float4*>(src + off + 4);
    uint4 o;
    o.x = cvtpk(a.x, a.y); o.y = cvtpk(a.z, a.w);
    o.z = cvtpk(b.x, b.y); o.w = cvtpk(b.z, b.w);
    *reinterpret_cast<uint4*>(Wb + (size_t)sel * 65536 + off) = o;
}

// ---------- Projection: q,k bf16 [B,S,D]; v transposed bf16 [B,D,S] ----------
__global__ __launch_bounds__(256) void proj_kernel(
    const float* __restrict__ x, const ushort* __restrict__ Wb,
    ushort* __restrict__ q_ws, ushort* __restrict__ k_ws, ushort* __restrict__ vT_ws)
{
    __shared__ __align__(16) ushort x_lds[64 * 64];
    __shared__ __align__(16) ushort w_lds[192 * 64];
    const int t = threadIdx.x;
    const int wid = t >> 6, lane = t & 63, g = lane >> 4, lr = lane & 15;
    const int m0 = blockIdx.x * 64;

    f32x4 acc[3][4];
#pragma unroll
    for (int ni = 0; ni < 3; ++ni)
#pragma unroll
        for (int mi = 0; mi < 4; ++mi) acc[ni][mi] = (f32x4)(0.0f);

    for (int e0 = 0; e0 < EE; e0 += 64) {
        // stage x tile 64x64 (f32 -> bf16, packed cvt)
#pragma unroll
        for (int i = 0; i < 4; ++i) {
            int idx = i * 256 + t;
            int row = idx >> 4, c4 = idx & 15;
            float4 v = *reinterpret_cast<const float4*>(&x[(size_t)(m0 + row) * EE + e0 + c4 * 4]);
            uint2 p; p.x = cvtpk(v.x, v.y); p.y = cvtpk(v.z, v.w);
            *reinterpret_cast<uint2*>((char*)x_lds + row * 128 + SWZ16(row, c4 * 8)) = p;
        }
        // stage W tile 192x64 bf16
#pragma unroll
        for (int i = 0; i < 6; ++i) {
            int idx = i * 256 + t;
            int row = idx >> 3, c8 = idx & 7;
            uint4 v = *reinterpret_cast<const uint4*>(&Wb[(size_t)row * EE + e0 + c8 * 8]);
            *reinterpret_cast<uint4*>((char*)w_lds + row * 128 + SWZ16(row, c8 * 16)) = v;
        }
        __syncthreads();

        short8 af[3][2], bf[4][2];
#pragma unroll
        for (int ni = 0; ni < 3; ++ni)
#pragma unroll
            for (int c = 0; c < 2; ++c) {
                int row = wid * 48 + ni * 16 + lr;
                af[ni][c] = *reinterpret_cast<const short8*>((const char*)w_lds + row * 128 + SWZ16(row, c * 64 + g * 16));
            }
#pragma unroll
        for (int mi = 0; mi < 4; ++mi)
#pragma unroll
            for (int c = 0; c < 2; ++c) {
                int row = mi * 16 + lr;
                bf[mi][c] = *reinterpret_cast<const short8*>((const char*)x_lds + row * 128 + SWZ16(row, c * 64 + g * 16));
            }
#pragma unroll
        for (int ni = 0; ni < 3; ++ni)
#pragma unroll
            for (int mi = 0; mi < 4; ++mi)
#pragma unroll
                for (int c = 0; c < 2; ++c)
                    acc[ni][mi] = __builtin_amdgcn_mfma_f32_16x16x32_bf16(af[ni][c], bf[mi][c], acc[ni][mi], 0, 0, 0);
        __syncthreads();
    }

    // epilogue: D[n][m]: n = wid*48+ni*16+4g+jr, m = m0+mi*16+lr
#pragma unroll
    for (int ni = 0; ni < 3; ++ni) {
        int n0 = wid * 48 + ni * 16 + 4 * g;
        int sel = n0 >> 6, d0 = n0 & 63;
#pragma unroll
        for (int mi = 0; mi < 4; ++mi) {
            int m = m0 + mi * 16 + lr;
            int b = m >> 12, s = m & (SS - 1);
            uint2 p;
            p.x = cvtpk(acc[ni][mi][0], acc[ni][mi][1]);
            p.y = cvtpk(acc[ni][mi][2], acc[ni][mi][3]);
            if (sel == 0) {
                *reinterpret_cast<uint2*>(q_ws + ((size_t)b * SS + s) * DD + d0) = p;
            } else if (sel == 1) {
                *reinterpret_cast<uint2*>(k_ws + ((size_t)b * SS + s) * DD + d0) = p;
            } else {
                ushort e0 = (ushort)(p.x & 0xFFFF), e1 = (ushort)(p.x >> 16);
                ushort e2 = (ushort)(p.y & 0xFFFF), e3 = (ushort)(p.y >> 16);
                vT_ws[((size_t)b * DD + d0 + 0) * SS + s] = e0;
                vT_ws[((size_t)b * DD + d0 + 1) * SS + s] = e1;
                vT_ws[((size_t)b * DD + d0 + 2) * SS + s] = e2;
                vT_ws[((size_t)b * DD + d0 + 3) * SS + s] = e3;
            }
        }
    }
}

// ---------- Flash attention: 1 wave / 16 q-rows, swapped QK^T, reg-dbuf K/V ----------
__global__ __launch_bounds__(64) void attn_kernel(
    const ushort* __restrict__ q_ws, const ushort* __restrict__ k_ws,
    const ushort* __restrict__ vT_ws, float* __restrict__ out)
{
    __shared__ __align__(16) ushort P_lds[16 * 72];
    const int lane = threadIdx.x, g = lane >> 4, lr = lane & 15;
    const int bid = blockIdx.x;
    const int b = bid & (BB - 1);
    const int qt = 255 - (bid >> 2);      // heavy q-tiles first
    const int qb = qt * 16;

    const ushort* qp = q_ws + ((size_t)b * SS + qb + lr) * DD;
    short8 qf0 = *reinterpret_cast<const short8*>(qp + g * 8);
    short8 qf1 = *reinterpret_cast<const short8*>(qp + 32 + g * 8);

    float m_r = -1e30f, l_r = 0.0f;
    f32x4 acc[4];
#pragma unroll
    for (int i = 0; i < 4; ++i) acc[i] = (f32x4)(0.0f);

    const float sc = 0.125f * 1.44269504f;
    const int nt = (qb + 79) >> 6;        // total kv tiles of 64
    const int nfull = (qb + 1) >> 6;      // maskless tiles
    const ushort* kbase = k_ws + (size_t)b * SS * DD;
    const ushort* vbase = vT_ws + (size_t)b * DD * SS;

    short8 bufA[16], bufB[16];

#define LOADT(BUF, KT) do { \
    int kv0_ = (KT) * 64; \
    _Pragma("unroll") \
    for (int nf = 0; nf < 4; ++nf) { \
        const ushort* kp_ = kbase + (size_t)(kv0_ + nf * 16 + lr) * DD; \
        BUF[nf * 2 + 0] = *reinterpret_cast<const short8*>(kp_ + g * 8); \
        BUF[nf * 2 + 1] = *reinterpret_cast<const short8*>(kp_ + 32 + g * 8); \
    } \
    _Pragma("unroll") \
    for (int df = 0; df < 4; ++df) { \
        const ushort* vp_ = vbase + (size_t)(df * 16 + lr) * SS + kv0_; \
        BUF[8 + df * 2 + 0] = *reinterpret_cast<const short8*>(vp_ + g * 8); \
        BUF[8 + df * 2 + 1] = *reinterpret_cast<const short8*>(vp_ + 32 + g * 8); \
    } \
} while (0)

#define COMPUTE(BUF, KT) do { \
    int kv0_ = (KT) * 64; \
    f32x4 sfr[4]; \
    _Pragma("unroll") \
    for (int nf = 0; nf < 4; ++nf) { \
        f32x4 s_ = (f32x4)(0.0f); \
        s_ = __builtin_amdgcn_mfma_f32_16x16x32_bf16(BUF[nf * 2 + 0], qf0, s_, 0, 0, 0); \
        s_ = __builtin_amdgcn_mfma_f32_16x16x32_bf16(BUF[nf * 2 + 1], qf1, s_, 0, 0, 0); \
        sfr[nf] = s_; \
    } \
    _Pragma("unroll") \
    for (int nf = 0; nf < 4; ++nf) sfr[nf] *= sc; \
    if ((KT) >= nfull) { \
        _Pragma("unroll") \
        for (int nf = 0; nf < 4; ++nf) \
            _Pragma("unroll") \
            for (int jr = 0; jr < 4; ++jr) \
                if (kv0_ + nf * 16 + 4 * g + jr > qb + lr) sfr[nf][jr] = -1e30f; \
    } \
    float mt = fmaxf(fmaxf(fmaxf(sfr[0][0], sfr[0][1]), fmaxf(sfr[0][2], sfr[0][3])), \
                     fmaxf(fmaxf(sfr[1][0], sfr[1][1]), fmaxf(sfr[1][2], sfr[1][3]))); \
    mt = fmaxf(mt, fmaxf(fmaxf(fmaxf(sfr[2][0], sfr[2][1]), fmaxf(sfr[2][2], sfr[2][3])), \
                         fmaxf(fmaxf(sfr[3][0], sfr[3][1]), fmaxf(sfr[3][2], sfr[3][3])))); \
    mt = fmaxf(mt, __shfl_xor(mt, 16)); \
    mt = fmaxf(mt, __shfl_xor(mt, 32)); \
    float mn = fmaxf(m_r, mt); \
    float sf = exp2f(m_r - mn); \
    m_r = mn; \
    float ps = 0.0f; \
    uint32_t pk[8]; \
    _Pragma("unroll") \
    for (int nf = 0; nf < 4; ++nf) { \
        float e0_ = exp2f(sfr[nf][0] - mn); \
        float e1_ = exp2f(sfr[nf][1] - mn); \
        float e2_ = exp2f(sfr[nf][2] - mn); \
        float e3_ = exp2f(sfr[nf][3] - mn); \
        ps += (e0_ + e1_) + (e2_ + e3_); \
        pk[nf * 2 + 0] = cvtpk(e0_, e1_); \
        pk[nf * 2 + 1] = cvtpk(e2_, e3_); \
    } \
    ps += __shfl_xor(ps, 16); \
    ps += __shfl_xor(ps, 32); \
    l_r = l_r * sf + ps; \
    _Pragma("unroll") \
    for (int df = 0; df < 4; ++df) acc[df] *= sf; \
    _Pragma("unroll") \
    for (int nf = 0; nf < 4; ++nf) { \
        uint2 w_; w_.x = pk[nf * 2]; w_.y = pk[nf * 2 + 1]; \
        *reinterpret_cast<uint2*>(&P_lds[lr * 72 + nf * 16 + 4 * g]) = w_; \
    } \
    _Pragma("unroll") \
    for (int c = 0; c < 2; ++c) { \
        short8 pb_ = *reinterpret_cast<const short8*>(&P_lds[lr * 72 + c * 32 + g * 8]); \
        _Pragma("unroll") \
        for (int df = 0; df < 4; ++df) \
            acc[df] = __builtin_amdgcn_mfma_f32_16x16x32_bf16(BUF[8 + df * 2 + c], pb_, acc[df], 0, 0, 0); \
    } \
} while (0)

    LOADT(bufA, 0);
    int kt = 0;
    while (true) {
        if (kt + 1 < nt) LOADT(bufB, kt + 1);
        COMPUTE(bufA, kt);
        ++kt; if (kt >= nt) break;
        if (kt + 1 < nt) LOADT(bufA, kt + 1);
        COMPUTE(bufB, kt);
        ++kt; if (kt >= nt) break;
    }

    // epilogue: acc[df] = O^T[d = df*16+4g+jr][q = lr]
    float inv = 1.0f / l_r;
    float* op = out + ((size_t)b * SS + qb + lr) * DD;
#pragma unroll
    for (int df = 0; df < 4; ++df) {
        f32x4 o = acc[df] * inv;
        float4 st; st.x = o[0]; st.y = o[1]; st.z = o[2]; st.w = o[3];
        *reinterpret_cast<float4*>(op + df * 16 + 4 * g) = st;
    }
}

extern "C" void kernel_launch(void* const* d_in, const int* in_sizes, int n_in,
                              void* d_out, int out_size, void* d_ws, size_t ws_size,
                              hipStream_t stream) {
    const float* x  = (const float*)d_in[0];
    const float* Wk = (const float*)d_in[1];
    const float* Wq = (const float*)d_in[2];
    const float* Wv = (const float*)d_in[3];
    ushort* q_ws  = (ushort*)d_ws;
    ushort* k_ws  = q_ws + (size_t)BB * SS * DD;
    ushort* vT_ws = k_ws + (size_t)BB * SS * DD;
    ushort* Wb    = vT_ws + (size_t)BB * SS * DD;
    float* out = (float*)d_out;

    hipLaunchKernelGGL(wconv_kernel, dim3(96), dim3(256), 0, stream, Wq, Wk, Wv, Wb);
    hipLaunchKernelGGL(proj_kernel, dim3(BB * SS / 64), dim3(256), 0, stream,
                       x, Wb, q_ws, k_ws, vT_ws);
    hipLaunchKernelGGL(attn_kernel, dim3(BB * SS / 16), dim3(64), 0, stream,
                       q_ws, k_ws, vT_ws, out);
}